// Round 2
// baseline (1271.826 us; speedup 1.0000x reference)
//
#include <hip/hip_runtime.h>

typedef unsigned short ushort_t;
using floatx4 = __attribute__((ext_vector_type(4))) float;
using shortx8 = __attribute__((ext_vector_type(8))) short;

#define NROWS_E 131072            // B*V*V per edge tensor
#define E_ELEMS 33554432          // NROWS_E * 256
#define H_ROWS  512               // B*V
#define H_ELEMS 131072            // H_ROWS * 256

__device__ __forceinline__ ushort_t f2bf(float f) {
    union { float f; unsigned int u; } x; x.f = f;
    unsigned int r = (x.u + 0x7FFFu + ((x.u >> 16) & 1u)) >> 16;
    return (ushort_t)r;
}

// ---------------- K0: convert W slots {8,11,14} to bf16 ----------------
__global__ void k_convW(const float* __restrict__ Ws, ushort_t* __restrict__ Wb) {
    int idx = blockIdx.x * 256 + threadIdx.x;     // 196608 total
    int t = idx >> 16;
    int r = idx & 65535;
    int slot = (t == 0) ? 8 : (t == 1) ? 11 : 14;
    Wb[idx] = f2bf(Ws[slot * 65536 + r]);
}

// ---------------- K1: 12 small linears (fp32 tiled 64x64) ----------------
__launch_bounds__(256)
__global__ void k_lin(const float* __restrict__ hsc, const float* __restrict__ hst,
                      const float* __restrict__ Ws, const float* __restrict__ bs,
                      float* __restrict__ tH) {
    // grid = 12 slots * 8 mtiles * 4 ntiles = 384
    int bx = blockIdx.x;
    int s = bx >> 5; int rem = bx & 31; int mt = rem >> 2; int nt = rem & 3;
    const int wsl[12] = {0,1,2,3,4,5,6,7,9,10,12,13};
    const int xst[12] = {0,1,0,1,0,1,0,1,0,0,1,1};
    int wslot = wsl[s];
    const float* x = xst[s] ? hst : hsc;
    int m0 = mt * 64, n0 = nt * 64;
    __shared__ float Xs[64][33];
    __shared__ float Wt[64][33];
    int tid = threadIdx.x;
    int tn = tid & 15, tm = tid >> 4;
    float acc[4][4] = {};
    for (int kk = 0; kk < 8; ++kk) {
        int k0 = kk * 32;
        #pragma unroll
        for (int u = tid; u < 2048; u += 256) {
            int r = u >> 5, k = u & 31;
            Xs[r][k] = x[(m0 + r) * 256 + k0 + k];
            Wt[r][k] = Ws[wslot * 65536 + (n0 + r) * 256 + k0 + k];
        }
        __syncthreads();
        #pragma unroll
        for (int k = 0; k < 32; ++k) {
            float a[4], b[4];
            #pragma unroll
            for (int i = 0; i < 4; ++i) a[i] = Xs[tm*4+i][k];
            #pragma unroll
            for (int j = 0; j < 4; ++j) b[j] = Wt[tn*4+j][k];
            #pragma unroll
            for (int i = 0; i < 4; ++i)
                #pragma unroll
                for (int j = 0; j < 4; ++j) acc[i][j] += a[i]*b[j];
        }
        __syncthreads();
    }
    #pragma unroll
    for (int i = 0; i < 4; ++i)
        #pragma unroll
        for (int j = 0; j < 4; ++j) {
            int n = n0 + tn*4 + j;
            tH[(long)s * H_ELEMS + (long)(m0 + tm*4 + i) * 256 + n] = acc[i][j] + bs[wslot*256 + n];
        }
}

// ---------------- K2: pass 1 — barrier-free MFMA GEMM + stats + gated agg ----------
// No LDS, no __syncthreads. A fragments loaded per-lane from e (f32->bf16 in regs),
// B fragments loaded per-lane from Wb (L2-resident). Register double-buffered.
__launch_bounds__(256)
__global__ void k_pass1(const float* __restrict__ e_bi, const float* __restrict__ e_sc,
                        const float* __restrict__ e_st,
                        const float* __restrict__ tH, const ushort_t* __restrict__ Wb,
                        const float* __restrict__ bs,
                        float* __restrict__ accSc, float* __restrict__ accSt,
                        float* __restrict__ S1, float* __restrict__ S2) {
    int bx = blockIdx.x;
    int t = bx >> 11;              // 2048 m-tiles / tensor
    int rem = bx & 2047;
    int b = rem >> 10;
    int rem2 = rem & 1023;
    int i0 = (rem2 >> 5) * 8;
    int j0 = (rem2 & 31) * 8;

    const float *e, *tA, *tB, *wj, *wi;
    int doSj, doSi, slotC;
    if (t == 0)      { e = e_bi; tA = tH + 6L*H_ELEMS; tB = tH + 7L*H_ELEMS; wj = tH + 3L*H_ELEMS; wi = tH + 2L*H_ELEMS; doSj = 1; doSi = 1; slotC = 8; }
    else if (t == 1) { e = e_sc; tA = tH + 8L*H_ELEMS; tB = tH + 9L*H_ELEMS; wj = tH + 4L*H_ELEMS; wi = tH;             doSj = 1; doSi = 0; slotC = 11; }
    else             { e = e_st; tA = tH + 10L*H_ELEMS; tB = tH + 11L*H_ELEMS; wj = tH;            wi = tH + 5L*H_ELEMS; doSj = 0; doSi = 1; slotC = 14; }

    const ushort_t* WbT = Wb + (long)t * 65536;
    int tid = threadIdx.x;
    int lane = tid & 63;
    int wave_n = tid >> 6;
    int fc = lane & 15;
    int quad = lane >> 4;

    // per-lane A row bases: local row mloc = mt*16 + fc -> (iloc = mloc>>3, jloc = mloc&7)
    long abase[4];
    #pragma unroll
    for (int mt = 0; mt < 4; ++mt) {
        int mloc = mt*16 + fc;
        abase[mt] = ((long)(b*256 + i0 + (mloc >> 3)) * 256 + (j0 + (mloc & 7))) * 256 + quad*8;
    }
    // per-lane B base: row n = wave_n*64 + nt*16 + fc, k-chunk = quad*8
    long bbase = (long)(wave_n*64 + fc) * 256 + quad*8;

    floatx4 acc[4][4];
    #pragma unroll
    for (int i = 0; i < 4; ++i)
        #pragma unroll
        for (int j = 0; j < 4; ++j) acc[i][j] = (floatx4){0.f, 0.f, 0.f, 0.f};

    // prologue: load kk=0 tiles
    float4 a0[4], a1[4];
    shortx8 bfv[4];
    #pragma unroll
    for (int mt = 0; mt < 4; ++mt) {
        a0[mt] = *(const float4*)(e + abase[mt]);
        a1[mt] = *(const float4*)(e + abase[mt] + 4);
    }
    #pragma unroll
    for (int nt = 0; nt < 4; ++nt)
        bfv[nt] = *(const shortx8*)(WbT + bbase + nt*4096);

    #pragma unroll 2
    for (int kk = 0; kk < 8; ++kk) {
        float4 c0[4], c1[4]; shortx8 cb[4];
        if (kk < 7) {
            int k0 = (kk + 1) * 32;
            #pragma unroll
            for (int mt = 0; mt < 4; ++mt) {
                c0[mt] = *(const float4*)(e + abase[mt] + k0);
                c1[mt] = *(const float4*)(e + abase[mt] + k0 + 4);
            }
            #pragma unroll
            for (int nt = 0; nt < 4; ++nt)
                cb[nt] = *(const shortx8*)(WbT + bbase + nt*4096 + k0);
        }
        shortx8 af[4];
        #pragma unroll
        for (int mt = 0; mt < 4; ++mt) {
            shortx8 pk;
            pk[0] = (short)f2bf(a0[mt].x); pk[1] = (short)f2bf(a0[mt].y);
            pk[2] = (short)f2bf(a0[mt].z); pk[3] = (short)f2bf(a0[mt].w);
            pk[4] = (short)f2bf(a1[mt].x); pk[5] = (short)f2bf(a1[mt].y);
            pk[6] = (short)f2bf(a1[mt].z); pk[7] = (short)f2bf(a1[mt].w);
            af[mt] = pk;
        }
        #pragma unroll
        for (int nt = 0; nt < 4; ++nt)
            #pragma unroll
            for (int mt = 0; mt < 4; ++mt)
                acc[mt][nt] = __builtin_amdgcn_mfma_f32_16x16x32_bf16(af[mt], bfv[nt], acc[mt][nt], 0, 0, 0);
        if (kk < 7) {
            #pragma unroll
            for (int mt = 0; mt < 4; ++mt) { a0[mt] = c0[mt]; a1[mt] = c1[mt]; }
            #pragma unroll
            for (int nt = 0; nt < 4; ++nt) bfv[nt] = cb[nt];
        }
    }

    // epilogue: stats + gated aggregation (operands direct from L2-warm global)
    float s1[4], s2[4];
    #pragma unroll
    for (int nt = 0; nt < 4; ++nt) { s1[nt] = 0.f; s2[nt] = 0.f; }
    float sst[4][4] = {};

    #pragma unroll
    for (int nt = 0; nt < 4; ++nt) {
        int cloc = wave_n*64 + nt*16 + fc;
        float bias_c = bs[slotC*256 + cloc];
        float tBv[4], wjv[4];
        #pragma unroll
        for (int r = 0; r < 4; ++r) {
            int jloc = (quad & 1)*4 + r;
            long jidx = (long)(b*256 + j0 + jloc)*256 + cloc;
            tBv[r] = tB[jidx] + bias_c;
            wjv[r] = doSj ? wj[jidx] : 0.f;
        }
        #pragma unroll
        for (int mt = 0; mt < 4; ++mt) {
            int iloc = 2*mt + (quad >> 1);
            long iidx = (long)(b*256 + i0 + iloc)*256 + cloc;
            float tAv = tA[iidx];
            float wiv = doSi ? wi[iidx] : 0.f;
            float p = 0.f;
            #pragma unroll
            for (int r = 0; r < 4; ++r) {
                float v = acc[mt][nt][r] + tAv + tBv[r];
                s1[nt] += v; s2[nt] += v*v;
                float g = 1.f / (1.f + __expf(-v));
                if (doSj) p += g * wjv[r];
                if (doSi) sst[nt][r] += g * wiv;
            }
            if (doSj) {
                p += __shfl_xor(p, 16);
                if ((quad & 1) == 0)
                    atomicAdd(&accSc[iidx], p);
            }
        }
        if (doSi) {
            #pragma unroll
            for (int r = 0; r < 4; ++r) {
                float vv = sst[nt][r] + __shfl_xor(sst[nt][r], 32);
                if (quad < 2) {
                    int jloc = (quad & 1)*4 + r;
                    atomicAdd(&accSt[(long)(b*256 + j0 + jloc)*256 + cloc], vv);
                }
            }
        }
        float a1s = s1[nt]; a1s += __shfl_xor(a1s, 16); a1s += __shfl_xor(a1s, 32);
        float a2s = s2[nt]; a2s += __shfl_xor(a2s, 16); a2s += __shfl_xor(a2s, 32);
        if (quad == 0) {
            atomicAdd(&S1[t*256 + cloc], a1s);
            atomicAdd(&S2[t*256 + cloc], a2s);
        }
    }
}

// ---------------- K_bnp: edge BN affine params ----------------
__global__ void k_bnp(const float* __restrict__ S1, const float* __restrict__ S2,
                      const float* __restrict__ ge, const float* __restrict__ be,
                      float* __restrict__ scale, float* __restrict__ shift) {
    int t = blockIdx.x, c = threadIdx.x;
    float N = (float)NROWS_E;
    float mean = S1[t*256 + c] / N;
    float var = S2[t*256 + c] / N - mean*mean;
    float rs = rsqrtf(var + 1e-5f);
    float sc = ge[c] * rs;
    scale[t*256 + c] = sc;
    shift[t*256 + c] = be[c] - sc * mean;
}

// ---------------- K3: h finalize (BN over 512 rows + relu + residual) ----------------
__global__ void k_hfin(const float* __restrict__ tH, const float* __restrict__ accSc,
                       const float* __restrict__ accSt,
                       const float* __restrict__ hsc, const float* __restrict__ hst,
                       const float* __restrict__ gh, const float* __restrict__ bh,
                       float* __restrict__ outp) {
    int tau = blockIdx.x >> 8;
    int c = blockIdx.x & 255;
    const float* U = tH + (tau ? (long)H_ELEMS : 0L);
    const float* A = tau ? accSt : accSc;
    const float* hin = tau ? hst : hsc;
    int lane = threadIdx.x;   // 64
    float v[8]; float s1 = 0.f, s2 = 0.f;
    #pragma unroll
    for (int k = 0; k < 8; ++k) {
        int row = lane + k*64;
        float x = U[(long)row*256 + c] + A[(long)row*256 + c];
        v[k] = x; s1 += x; s2 += x*x;
    }
    #pragma unroll
    for (int off = 1; off < 64; off <<= 1) { s1 += __shfl_xor(s1, off); s2 += __shfl_xor(s2, off); }
    float mean = s1 / 512.f;
    float var = s2 / 512.f - mean*mean;
    float rs = rsqrtf(var + 1e-5f);
    float gc = gh[c], bc = bh[c];
    #pragma unroll
    for (int k = 0; k < 8; ++k) {
        int row = lane + k*64;
        float y = gc * (v[k] - mean) * rs + bc;
        outp[(long)tau*H_ELEMS + (long)row*256 + c] = hin[(long)row*256 + c] + fmaxf(y, 0.f);
    }
}

// ---------------- K4: pass 2 — recompute v, fused BN+relu+residual, write out ------
// Same barrier-free GEMM core as pass 1; epilogue applies BN affine + relu + residual.
__launch_bounds__(256)
__global__ void k_pass2(const float* __restrict__ e_bi, const float* __restrict__ e_sc,
                        const float* __restrict__ e_st,
                        const float* __restrict__ tH, const ushort_t* __restrict__ Wb,
                        const float* __restrict__ bs,
                        const float* __restrict__ bnScale, const float* __restrict__ bnShift,
                        float* __restrict__ outE) {
    int bx = blockIdx.x;
    int t = bx >> 11;
    int rem = bx & 2047;
    int b = rem >> 10;
    int rem2 = rem & 1023;
    int i0 = (rem2 >> 5) * 8;
    int j0 = (rem2 & 31) * 8;

    const float *e, *tA, *tB;
    int slotC;
    if (t == 0)      { e = e_bi; tA = tH + 6L*H_ELEMS; tB = tH + 7L*H_ELEMS; slotC = 8; }
    else if (t == 1) { e = e_sc; tA = tH + 8L*H_ELEMS; tB = tH + 9L*H_ELEMS; slotC = 11; }
    else             { e = e_st; tA = tH + 10L*H_ELEMS; tB = tH + 11L*H_ELEMS; slotC = 14; }

    const ushort_t* WbT = Wb + (long)t * 65536;
    int tid = threadIdx.x;
    int lane = tid & 63;
    int wave_n = tid >> 6;
    int fc = lane & 15;
    int quad = lane >> 4;

    long abase[4];
    #pragma unroll
    for (int mt = 0; mt < 4; ++mt) {
        int mloc = mt*16 + fc;
        abase[mt] = ((long)(b*256 + i0 + (mloc >> 3)) * 256 + (j0 + (mloc & 7))) * 256 + quad*8;
    }
    long bbase = (long)(wave_n*64 + fc) * 256 + quad*8;

    floatx4 acc[4][4];
    #pragma unroll
    for (int i = 0; i < 4; ++i)
        #pragma unroll
        for (int j = 0; j < 4; ++j) acc[i][j] = (floatx4){0.f, 0.f, 0.f, 0.f};

    float4 a0[4], a1[4];
    shortx8 bfv[4];
    #pragma unroll
    for (int mt = 0; mt < 4; ++mt) {
        a0[mt] = *(const float4*)(e + abase[mt]);
        a1[mt] = *(const float4*)(e + abase[mt] + 4);
    }
    #pragma unroll
    for (int nt = 0; nt < 4; ++nt)
        bfv[nt] = *(const shortx8*)(WbT + bbase + nt*4096);

    #pragma unroll 2
    for (int kk = 0; kk < 8; ++kk) {
        float4 c0[4], c1[4]; shortx8 cb[4];
        if (kk < 7) {
            int k0 = (kk + 1) * 32;
            #pragma unroll
            for (int mt = 0; mt < 4; ++mt) {
                c0[mt] = *(const float4*)(e + abase[mt] + k0);
                c1[mt] = *(const float4*)(e + abase[mt] + k0 + 4);
            }
            #pragma unroll
            for (int nt = 0; nt < 4; ++nt)
                cb[nt] = *(const shortx8*)(WbT + bbase + nt*4096 + k0);
        }
        shortx8 af[4];
        #pragma unroll
        for (int mt = 0; mt < 4; ++mt) {
            shortx8 pk;
            pk[0] = (short)f2bf(a0[mt].x); pk[1] = (short)f2bf(a0[mt].y);
            pk[2] = (short)f2bf(a0[mt].z); pk[3] = (short)f2bf(a0[mt].w);
            pk[4] = (short)f2bf(a1[mt].x); pk[5] = (short)f2bf(a1[mt].y);
            pk[6] = (short)f2bf(a1[mt].z); pk[7] = (short)f2bf(a1[mt].w);
            af[mt] = pk;
        }
        #pragma unroll
        for (int nt = 0; nt < 4; ++nt)
            #pragma unroll
            for (int mt = 0; mt < 4; ++mt)
                acc[mt][nt] = __builtin_amdgcn_mfma_f32_16x16x32_bf16(af[mt], bfv[nt], acc[mt][nt], 0, 0, 0);
        if (kk < 7) {
            #pragma unroll
            for (int mt = 0; mt < 4; ++mt) { a0[mt] = c0[mt]; a1[mt] = c1[mt]; }
            #pragma unroll
            for (int nt = 0; nt < 4; ++nt) bfv[nt] = cb[nt];
        }
    }

    long outBase = (long)t * E_ELEMS;
    #pragma unroll
    for (int nt = 0; nt < 4; ++nt) {
        int cloc = wave_n*64 + nt*16 + fc;
        float bias_c = bs[slotC*256 + cloc];
        float sc = bnScale[t*256 + cloc];
        float sh = bnShift[t*256 + cloc];
        float tBv[4];
        #pragma unroll
        for (int r = 0; r < 4; ++r) {
            int jloc = (quad & 1)*4 + r;
            tBv[r] = tB[(long)(b*256 + j0 + jloc)*256 + cloc] + bias_c;
        }
        #pragma unroll
        for (int mt = 0; mt < 4; ++mt) {
            int iloc = 2*mt + (quad >> 1);
            float tAv = tA[(long)(b*256 + i0 + iloc)*256 + cloc];
            #pragma unroll
            for (int r = 0; r < 4; ++r) {
                int jloc = (quad & 1)*4 + r;
                float v = acc[mt][nt][r] + tAv + tBv[r];
                long grow = ((long)(b*256 + i0 + iloc)*256 + (j0 + jloc))*256 + cloc;
                outE[outBase + grow] = e[grow] + fmaxf(sc*v + sh, 0.f);
            }
        }
    }
}

extern "C" void kernel_launch(void* const* d_in, const int* in_sizes, int n_in,
                              void* d_out, int out_size, void* d_ws, size_t ws_size,
                              hipStream_t stream) {
    (void)in_sizes; (void)n_in; (void)out_size; (void)ws_size;
    const float* h_sc = (const float*)d_in[0];
    const float* h_st = (const float*)d_in[1];
    const float* bi_e = (const float*)d_in[2];
    const float* sc_e = (const float*)d_in[4];
    const float* st_e = (const float*)d_in[6];
    const float* Ws   = (const float*)d_in[8];
    const float* bs   = (const float*)d_in[9];
    const float* gh   = (const float*)d_in[10];
    const float* bh   = (const float*)d_in[11];
    const float* ge   = (const float*)d_in[12];
    const float* be   = (const float*)d_in[13];
    float* out = (float*)d_out;

    float* ws = (float*)d_ws;
    float* tH      = ws;                 // 12*131072
    float* accSc   = ws + 1572864;       // 131072
    float* accSt   = ws + 1703936;       // 131072
    float* S1      = ws + 1835008;       // 768
    float* S2      = ws + 1835776;       // 768
    float* bnScale = ws + 1836544;       // 768
    float* bnShift = ws + 1837312;       // 768
    ushort_t* Wb   = (ushort_t*)(ws + 1838080);  // 196608 bf16

    // zero: accSc, accSt, S1, S2 (contiguous)
    hipMemsetAsync(accSc, 0, (size_t)(131072*2 + 1536) * sizeof(float), stream);
    k_convW<<<768, 256, 0, stream>>>(Ws, Wb);
    k_lin<<<384, 256, 0, stream>>>(h_sc, h_st, Ws, bs, tH);
    k_pass1<<<6144, 256, 0, stream>>>(bi_e, sc_e, st_e, tH, Wb, bs,
                                      accSc, accSt, S1, S2);
    k_bnp<<<3, 256, 0, stream>>>(S1, S2, ge, be, bnScale, bnShift);
    k_hfin<<<512, 64, 0, stream>>>(tH, accSc, accSt, h_sc, h_st, gh, bh, out);
    k_pass2<<<6144, 256, 0, stream>>>(bi_e, sc_e, st_e, tH, Wb, bs,
                                      bnScale, bnShift, out + 262144);
}